// Round 17
// baseline (215.160 us; speedup 1.0000x reference)
//
#include <hip/hip_runtime.h>

// NCA update via fp16 MFMA. R17: full-row waves, 32-col tiles, 2 px/lane.
// Lane p handles cols 32T+2p, 32T+2p+1 (s=0,1): float2 loads (128B granule,
// 2x fewer VMEM instrs), float2 stores, in-register neighbors for inner seams.
// Fragment/GEMM math identical to R13 (verified): DPP row shifts + ds_swizzle
// seams, pk_max ReLU, W2 pi-permutation, f32 blend mids.
// DPP: row_shr:1 = lane i<-i-1 (left; invalid p=0 keeps old=left seam);
//      row_shl:1 = lane i<-i+1 (right; invalid p=15 keeps old=right seam).

#define HH 512
#define WW 512
#define CC 16
#define HID 192
#define NT 16          // 32-col tiles per full row
#define HW (HH * WW)

typedef _Float16 half8  __attribute__((ext_vector_type(8)));
typedef _Float16 half2v __attribute__((ext_vector_type(2)));
typedef float    f32x2  __attribute__((ext_vector_type(2)));
typedef float    f32x4  __attribute__((ext_vector_type(4)));
typedef unsigned int u32;

__device__ __forceinline__ u32 h2i(half2v v) { return __builtin_bit_cast(u32, v); }
__device__ __forceinline__ half2v i2h(u32 v) { return __builtin_bit_cast(half2v, v); }
__device__ __forceinline__ u32 pkrtz(float a, float b) {
    return __builtin_bit_cast(u32, __builtin_amdgcn_cvt_pkrtz(a, b));
}
__device__ __forceinline__ u32 fi(float f) { return __builtin_bit_cast(u32, f); }
__device__ __forceinline__ float if_(u32 v) { return __builtin_bit_cast(float, v); }

#define SWZ_P15 0x1F0
#define SWZ_P0  0x0010
#define SWZ_LO  0x000F
#define SWZ(v, patt) ((u32)__builtin_amdgcn_ds_swizzle((int)(v), (patt)))
#define DPP_UP1(old, src) ((u32)__builtin_amdgcn_update_dpp((int)(old), (int)(src), 0x111, 0xF, 0xF, false))
#define DPP_DN1(old, src) ((u32)__builtin_amdgcn_update_dpp((int)(old), (int)(src), 0x101, 0xF, 0xF, false))

__global__ __launch_bounds__(256, 2) void nca_mfma_kernel(
    const float* __restrict__ x,
    const float* __restrict__ noise,
    const float* __restrict__ w1w,
    const float* __restrict__ w1b,
    const float* __restrict__ w2w,
    float* __restrict__ out)
{
    __shared__ __align__(16) float bl[HID];
    const int tid  = threadIdx.x;
    const int lane = tid & 63;
    const int wid  = tid >> 6;
    const int p    = lane & 15;
    const int gq   = lane >> 4;

    const int bid = blockIdx.x;
    const int lin = (bid & 7) * 64 + (bid >> 3);
    const int gr  = __builtin_amdgcn_readfirstlane(lin * 4 + wid); // row id 0..2047
    const int b   = gr >> 9;
    const int i   = gr & 511;

    for (int k = tid; k < HID; k += 256) bl[k] = w1b[k];
    __syncthreads();

    half8 w1f[12];
    #pragma unroll
    for (int t = 0; t < 12; ++t) {
        const float* src = w1w + (16 * t + p) * 32 + 8 * gq;
        #pragma unroll
        for (int e = 0; e < 8; ++e) w1f[t][e] = (_Float16)src[e];
    }
    const int pi_p = (p & 3) | ((p & 4) << 1) | ((p & 8) >> 1);
    half8 w2f[6];
    #pragma unroll
    for (int f = 0; f < 6; ++f) {
        const float* s0 = w2w + pi_p * HID + 32 * f + 4 * gq;
        #pragma unroll
        for (int e = 0; e < 4; ++e) {
            w2f[f][e]     = (_Float16)s0[e];
            w2f[f][4 + e] = (_Float16)s0[16 + e];
        }
    }

    const int im = (i == 0) ? HH - 1 : i - 1;
    const int ip = (i == HH - 1) ? 0 : i + 1;
    const float* xbch = x + ((size_t)b * CC + 8 * (gq & 1)) * HW;
    const float* pT = xbch + im * WW;
    const float* pM = xbch + (size_t)i * WW;
    const float* pB = xbch + ip * WW;
    const float* nrow = noise + (size_t)b * HW + (size_t)i * WW;
    float* orow = out + (size_t)b * CC * HW + (size_t)i * WW;

    const bool hiSel = (gq >= 2);
    const int gqsw = ((gq & 1) << 1) | (gq >> 1);

    f32x2 rT[8], rM[8], rB[8];
    auto loadRaw2 = [&](int base) {
        const int col = base + 2 * p;
        #pragma unroll
        for (int e = 0; e < 8; ++e) {
            rT[e] = *(const f32x2*)(pT + e * HW + col);
            rM[e] = *(const f32x2*)(pM + e * HW + col);
            rB[e] = *(const f32x2*)(pB + e * HW + col);
        }
    };
    auto combine2 = [&](u32 csw[2][4], u32 pmw[2][4], float mx[2][4], float cm[2]) {
        #pragma unroll
        for (int s = 0; s < 2; ++s) {
            #pragma unroll
            for (int w = 0; w < 4; ++w) {
                const float c0 = rT[2 * w][s] + rM[2 * w][s] + rB[2 * w][s];
                const float c1 = rT[2 * w + 1][s] + rM[2 * w + 1][s] + rB[2 * w + 1][s];
                csw[s][w] = pkrtz(c0, c1);
                pmw[s][w] = pkrtz(rM[2 * w][s], rM[2 * w + 1][s]);
            }
            #pragma unroll
            for (int j = 0; j < 4; ++j)
                mx[s][j] = hiSel ? rM[j + 4][s] : rM[j][s];
            cm[s] = fmaxf(fmaxf(rT[3][s], rM[3][s]), rB[3][s]);
        }
    };

    u32  cswB[2][4], pmwB[2][4], cswC[2][4], pmwC[2][4];
    float mxB[2][4], mxC[2][4];
    float cmB[2], cmC[2];
    f32x2 nzB, nzC;
    u32  cswA1[4];
    float cmA1;

    // prologue: halo col 511 (uniform) + tiles 0,1
    {
        float ht[8], hm[8], hb[8];
        #pragma unroll
        for (int e = 0; e < 8; ++e) {
            ht[e] = pT[e * HW + (WW - 1)];
            hm[e] = pM[e * HW + (WW - 1)];
            hb[e] = pB[e * HW + (WW - 1)];
        }
        #pragma unroll
        for (int w = 0; w < 4; ++w) {
            const float c0 = ht[2 * w] + hm[2 * w] + hb[2 * w];
            const float c1 = ht[2 * w + 1] + hm[2 * w + 1] + hb[2 * w + 1];
            cswA1[w] = pkrtz(c0, c1);
        }
        cmA1 = fmaxf(fmaxf(ht[3], hm[3]), hb[3]);

        loadRaw2(0);
        combine2(cswB, pmwB, mxB, cmB);
        nzB = *(const f32x2*)(nrow + 2 * p);
        loadRaw2(32);
        combine2(cswC, pmwC, mxC, cmC);
        nzC = *(const f32x2*)(nrow + 32 + 2 * p);
    }

    const f32x4* blv = (const f32x4*)bl;
    const half2v k9 = {(_Float16)9.0f, (_Float16)9.0f};
    const bool isCenter = (gq < 2);
    const u32 PZ = 0;

    auto gemm = [&](const half8& yv, float dx[4]) {
        f32x4 acc2a = {0.f, 0.f, 0.f, 0.f}, acc2b = {0.f, 0.f, 0.f, 0.f};
        #pragma unroll
        for (int f = 0; f < 6; ++f) {
            const f32x4 ba = blv[8 * f + gq];
            const f32x4 bb = blv[8 * f + 4 + gq];
            const f32x4 a1 = __builtin_amdgcn_mfma_f32_16x16x32_f16(w1f[2 * f],     yv, ba, 0, 0, 0);
            const f32x4 a2 = __builtin_amdgcn_mfma_f32_16x16x32_f16(w1f[2 * f + 1], yv, bb, 0, 0, 0);
            union { half8 v; u32 iw[4]; } hf;
            #pragma unroll
            for (int w = 0; w < 4; ++w) {
                const f32x4& aa = (w < 2) ? a1 : a2;
                const u32 pk = pkrtz(aa[2 * (w & 1)], aa[2 * (w & 1) + 1]);
                u32 rl;
                asm("v_pk_max_f16 %0, %1, %2" : "=v"(rl) : "v"(pk), "v"(PZ));
                hf.iw[w] = rl;
            }
            if (f & 1) acc2b = __builtin_amdgcn_mfma_f32_16x16x32_f16(w2f[f], hf.v, acc2b, 0, 0, 0);
            else       acc2a = __builtin_amdgcn_mfma_f32_16x16x32_f16(w2f[f], hf.v, acc2a, 0, 0, 0);
        }
        #pragma unroll
        for (int r = 0; r < 4; ++r) dx[r] = acc2a[r] + acc2b[r];
    };

    #pragma unroll 4
    for (int T = 0; T < NT; ++T) {
        // (1) issue raw + noise loads for tile T+2 (masked base; wrap tiles junk-but-valid)
        const int baseP = (32 * (T + 2)) & (WW - 1);
        loadRaw2(baseP);
        const f32x2 nzD = *(const f32x2*)(nrow + baseP + 2 * p);

        // (2) compute tile T -------------------------------------------
        union { half8 v; u32 iw[4]; } yf0, yf1;
        #pragma unroll
        for (int w = 0; w < 4; ++w) {
            // s=0 (col 2p): left = lane p-1's s1 (p=0 -> prev-tile lane15 s1); right = own s1
            const u32 lft0 = DPP_UP1(SWZ(cswA1[w], SWZ_P15), cswB[1][w]);
            const half2v s90 = i2h(lft0) + i2h(cswB[0][w]) + i2h(cswB[1][w]);
            const half2v lap0 = k9 * i2h(pmwB[0][w]) - s90;
            yf0.iw[w] = isCenter ? pmwB[0][w] : h2i(lap0);
            // s=1 (col 2p+1): left = own s0; right = lane p+1's s0 (p=15 -> next-tile lane0 s0)
            const u32 rgt1 = DPP_DN1(SWZ(cswC[0][w], SWZ_P0), cswB[0][w]);
            const half2v s91 = i2h(cswB[0][w]) + i2h(cswB[1][w]) + i2h(rgt1);
            const half2v lap1 = k9 * i2h(pmwB[1][w]) - s91;
            yf1.iw[w] = isCenter ? pmwB[1][w] : h2i(lap1);
        }

        // alive masks (ch3 3x3 max; valid in gq0/gq2, broadcast via SWZ_LO)
        const float ml0 = if_(DPP_UP1(SWZ(fi(cmA1), SWZ_P15), fi(cmB[1])));
        const float rmax0 = fmaxf(fmaxf(ml0, cmB[0]), cmB[1]);
        const float alive0 = (if_(SWZ(fi(rmax0), SWZ_LO)) > 0.1f) ? 1.0f : 0.0f;
        const float mr1 = if_(DPP_DN1(SWZ(fi(cmC[0]), SWZ_P0), fi(cmB[0])));
        const float rmax1 = fmaxf(fmaxf(cmB[0], cmB[1]), mr1);
        const float alive1 = (if_(SWZ(fi(rmax1), SWZ_LO)) > 0.1f) ? 1.0f : 0.0f;
        const float um0 = floorf(nzB[0] + 0.5f);
        const float um1 = floorf(nzB[1] + 0.5f);

        float dx0[4], dx1[4];
        gemm(yf0.v, dx0);
        gemm(yf1.v, dx1);

        // store float2 per channel
        const int col = 32 * T + 2 * p;
        #pragma unroll
        for (int r = 0; r < 4; ++r) {
            f32x2 v;
            v[0] = (mxB[0][r] + dx0[r] * um0) * alive0;
            v[1] = (mxB[1][r] + dx1[r] * um1) * alive1;
            *(f32x2*)(orow + (size_t)(4 * gqsw + r) * HW + col) = v;
        }

        // (3) combine tile T+2, rotate (A-seam captured BEFORE B is overwritten)
        u32 cswD[2][4], pmwD[2][4]; float mxD[2][4]; float cmD[2];
        combine2(cswD, pmwD, mxD, cmD);
        #pragma unroll
        for (int w = 0; w < 4; ++w) cswA1[w] = cswB[1][w];
        cmA1 = cmB[1];
        #pragma unroll
        for (int w = 0; w < 4; ++w) {
            #pragma unroll
            for (int s = 0; s < 2; ++s) {
                cswB[s][w] = cswC[s][w]; pmwB[s][w] = pmwC[s][w];
                cswC[s][w] = cswD[s][w]; pmwC[s][w] = pmwD[s][w];
            }
        }
        #pragma unroll
        for (int s = 0; s < 2; ++s) {
            #pragma unroll
            for (int j = 0; j < 4; ++j) { mxB[s][j] = mxC[s][j]; mxC[s][j] = mxD[s][j]; }
            cmB[s] = cmC[s]; cmC[s] = cmD[s];
        }
        nzB = nzC; nzC = nzD;
    }
}

extern "C" void kernel_launch(void* const* d_in, const int* in_sizes, int n_in,
                              void* d_out, int out_size, void* d_ws, size_t ws_size,
                              hipStream_t stream)
{
    const float* x     = (const float*)d_in[0];
    const float* noise = (const float*)d_in[1];
    const float* w1w   = (const float*)d_in[2];
    const float* w1b   = (const float*)d_in[3];
    const float* w2w   = (const float*)d_in[4];
    float* out = (float*)d_out;

    nca_mfma_kernel<<<512, 256, 0, stream>>>(x, noise, w1w, w1b, w2w, out);
}

// Round 18
// 61.869 us; speedup vs baseline: 3.4777x; 3.4777x over previous
//
#include <hip/hip_runtime.h>

// NCA update via fp16 MFMA, half-row-per-wave, software-pipelined.
// === R18 = R13 verbatim (best: 59.1 us) ===
// Structure: per 16-px tile, GEMM1 H=W1*Y+b (12x mfma 16x16x32), relu via
// v_pk_max_f16, GEMM2 dx=W2*relu(H) (6x mfma, H lane-local); perception via
// packed-fp16 column-sums, DPP row-shift neighbor exchange with ds_swizzle
// seam broadcasts; distance-2 prefetch (issue t+2 top, combine bottom).
// Negative results (all regressed vs this): R14 combine-first reorder (-14us,
// WAR serialization on rr), R15 U/V weight fold + fp16 blend-x (-13us),
// R16 distance-3 double-buffer (-10us), R17 2px/lane float2 (-156us, spill).
// R4: __launch_bounds__(256,4) clamps VGPR to 64 -> spill. Keep (256,2).
// DPP: row_shr:1 = lane i<-i-1 (left; invalid p=0 keeps old=left seam);
//      row_shl:1 = lane i<-i+1 (right; invalid p=15 keeps old=right seam).

#define HH 512
#define WW 512
#define CC 16
#define HID 192
#define NT 16          // tiles per wave (half row: 256 px)
#define HW (HH * WW)

typedef _Float16 half8  __attribute__((ext_vector_type(8)));
typedef _Float16 half2v __attribute__((ext_vector_type(2)));
typedef float    f32x4  __attribute__((ext_vector_type(4)));
typedef unsigned int u32;

__device__ __forceinline__ u32 h2i(half2v v) { return __builtin_bit_cast(u32, v); }
__device__ __forceinline__ half2v i2h(u32 v) { return __builtin_bit_cast(half2v, v); }
__device__ __forceinline__ u32 pkrtz(float a, float b) {
    return __builtin_bit_cast(u32, __builtin_amdgcn_cvt_pkrtz(a, b));
}
__device__ __forceinline__ u32 fi(float f) { return __builtin_bit_cast(u32, f); }
__device__ __forceinline__ float if_(u32 v) { return __builtin_bit_cast(float, v); }

// ds_swizzle patterns (BitMode): src_lane = ((lane & and) | or) ^ xor
#define SWZ_P15 0x1F0   // (lane&0x10)|0xF : p=15 of own 16-group
#define SWZ_P0  0x0010  // (lane&0x10)    : p=0  of own 16-group
#define SWZ_LO  0x000F  // lane&0xF       : same p in low group of 32-half

#define SWZ(v, patt) ((u32)__builtin_amdgcn_ds_swizzle((int)(v), (patt)))
// DPP row shifts (16-lane rows); invalid lanes keep `old` (bound_ctrl=false).
#define DPP_UP1(old, src) ((u32)__builtin_amdgcn_update_dpp((int)(old), (int)(src), 0x111, 0xF, 0xF, false))
#define DPP_DN1(old, src) ((u32)__builtin_amdgcn_update_dpp((int)(old), (int)(src), 0x101, 0xF, 0xF, false))

__global__ __launch_bounds__(256, 2) void nca_mfma_kernel(
    const float* __restrict__ x,
    const float* __restrict__ noise,
    const float* __restrict__ w1w,
    const float* __restrict__ w1b,
    const float* __restrict__ w2w,
    float* __restrict__ out)
{
    __shared__ __align__(16) float bl[HID];
    const int tid  = threadIdx.x;
    const int lane = tid & 63;
    const int wid  = tid >> 6;
    const int p    = lane & 15;   // pixel-in-tile / matrix row-col index
    const int gq   = lane >> 4;   // fragment k-group

    // XCD-aware swizzle: 1024 blocks -> 8 chunks of 128 consecutive blocks
    const int bid = blockIdx.x;
    const int lin = (bid & 7) * 128 + (bid >> 3);
    // wave-uniform scalars, forced into SGPRs
    const int gr    = __builtin_amdgcn_readfirstlane(lin * 4 + wid); // half-row id
    const int b     = gr >> 10;
    const int rem   = gr & 1023;
    const int i     = rem >> 1;             // image row
    const int start = (rem & 1) * (WW / 2); // which half

    // stage bias to LDS
    for (int k = tid; k < HID; k += 256) bl[k] = w1b[k];
    __syncthreads();

    // resident W1 A-fragments: lane holds W1[o=16t+p][c=8*gq+e]
    half8 w1f[12];
    #pragma unroll
    for (int t = 0; t < 12; ++t) {
        const float* src = w1w + (16 * t + p) * 32 + 8 * gq;
        #pragma unroll
        for (int e = 0; e < 8; ++e) w1f[t][e] = (_Float16)src[e];
    }
    // resident W2 A-fragments, rows permuted by pi(p)=swap bits2,3:
    // D-row m then holds W2-row pi(m), so gq group stores channels it staged.
    const int pi_p = (p & 3) | ((p & 4) << 1) | ((p & 8) >> 1);
    half8 w2f[6];
    #pragma unroll
    for (int f = 0; f < 6; ++f) {
        const float* s0 = w2w + pi_p * HID + 32 * f + 4 * gq;
        #pragma unroll
        for (int e = 0; e < 4; ++e) {
            w2f[f][e]     = (_Float16)s0[e];
            w2f[f][4 + e] = (_Float16)s0[16 + e];
        }
    }

    const int im = (i == 0) ? HH - 1 : i - 1;
    const int ip = (i == HH - 1) ? 0 : i + 1;
    const int rT = im * WW, rM = i * WW, rB = ip * WW;
    // uniform row-base pointers (SGPR pairs); per-lane part is col only
    const float* xbch = x + ((size_t)b * CC + 8 * (gq & 1)) * HW;
    const float* pT = xbch + rT;
    const float* pM = xbch + rM;
    const float* pB = xbch + rB;
    const float* nrow = noise + (size_t)b * HW + rM;
    float* orow = out + (size_t)b * CC * HW + rM;

    const bool hiSel = (gq >= 2);                  // blend mids from e=4..7?
    const int gqsw = ((gq & 1) << 1) | (gq >> 1);  // store channel group

    // raw loads: 8 channels x 3 rows at column `col` (uniform base + col)
    auto loadRaw = [&](int col, float r[24]) {
        #pragma unroll
        for (int e = 0; e < 8; ++e) {
            r[3 * e + 0] = pT[e * HW + col];
            r[3 * e + 1] = pM[e * HW + col];
            r[3 * e + 2] = pB[e * HW + col];
        }
    };
    // combine raws -> packed colsums, packed mids, f32 blend mids, ch3 col-max
    auto combine = [&](const float r[24], half2v pcs[4], half2v pm[4],
                       float mx[4], float& cm) {
        #pragma unroll
        for (int w = 0; w < 4; ++w) {
            const float cs0 = r[6 * w + 0] + r[6 * w + 1] + r[6 * w + 2];
            const float cs1 = r[6 * w + 3] + r[6 * w + 4] + r[6 * w + 5];
            pcs[w] = i2h(pkrtz(cs0, cs1));
            pm[w]  = i2h(pkrtz(r[6 * w + 1], r[6 * w + 4]));
        }
        #pragma unroll
        for (int j = 0; j < 4; ++j)
            mx[j] = hiSel ? r[3 * (j + 4) + 1] : r[3 * j + 1];
        cm = fmaxf(fmaxf(r[9], r[10]), r[11]);   // e==3 rows (ch3 for gq 0/2)
    };

    half2v pcsA[4], pcsB[4], pcsC[4], pmB[4], pmC[4];
    float  mxB[4], mxC[4];
    float  cmA, cmB, cmC;
    float  nzB, nzC;
    float  rr[24];

    // prologue: uniform-column halo (all lanes hold colsum of col start-1)
    {
        float rh[24]; half2v dum[4]; float dmx[4];
        loadRaw((start - 1) & (WW - 1), rh);
        combine(rh, pcsA, dum, dmx, cmA);
        float r0[24];
        loadRaw(start + p, r0);
        combine(r0, pcsB, pmB, mxB, cmB);
        float r1[24];
        loadRaw(start + 16 + p, r1);
        combine(r1, pcsC, pmC, mxC, cmC);
        nzB = nrow[start + p];
        nzC = nrow[start + 16 + p];
    }

    const f32x4* blv = (const f32x4*)bl;
    const half2v k9 = {(_Float16)9.0f, (_Float16)9.0f};
    const bool isCenter = (gq < 2);
    const u32 PZ = 0;   // packed fp16 zero for v_pk_max_f16

    #pragma unroll 4
    for (int t = 0; t < NT; ++t) {
        // (1) issue raw + noise loads for tile t+2 (masked col; tail iters junk-but-valid)
        const int colP = (start + 16 * (t + 2) + p) & (WW - 1);
        loadRaw(colP, rr);
        const float nzD = nrow[colP];

        // (2) compute tile t ------------------------------------------------
        union { half8 v; u32 iw[4]; } yf;
        #pragma unroll
        for (int w = 0; w < 4; ++w) {
            const u32 bw = h2i(pcsB[w]);
            const u32 pl = SWZ(h2i(pcsA[w]), SWZ_P15);   // left seam value
            const u32 pr = SWZ(h2i(pcsC[w]), SWZ_P0);    // right seam value
            const u32 lft = DPP_UP1(pl, bw);             // cs[p-1], p=0  -> pl
            const u32 rgt = DPP_DN1(pr, bw);             // cs[p+1], p=15 -> pr
            const half2v s9  = i2h(lft) + i2h(bw) + i2h(rgt);
            const half2v lap = k9 * pmB[w] - s9;
            yf.iw[w] = isCenter ? h2i(pmB[w]) : h2i(lap);
        }

        // alive mask (3x3 circular max of channel 3; valid in gq 0/2, broadcast)
        const u32 pml = SWZ(fi(cmA), SWZ_P15);
        const u32 pmr = SWZ(fi(cmC), SWZ_P0);
        const float ml = if_(DPP_UP1(pml, fi(cmB)));
        const float mr = if_(DPP_DN1(pmr, fi(cmB)));
        const float rmax  = fmaxf(fmaxf(ml, cmB), mr);
        const float av    = if_(SWZ(fi(rmax), SWZ_LO));
        const float alive = (av > 0.1f) ? 1.0f : 0.0f;
        const float um    = floorf(nzB + 0.5f);

        // GEMM1 + relu + GEMM2 (H stays lane-local)
        f32x4 acc2a = {0.f, 0.f, 0.f, 0.f}, acc2b = {0.f, 0.f, 0.f, 0.f};
        #pragma unroll
        for (int f = 0; f < 6; ++f) {
            const f32x4 ba = blv[8 * f + gq];
            const f32x4 bb = blv[8 * f + 4 + gq];
            const f32x4 a1 = __builtin_amdgcn_mfma_f32_16x16x32_f16(w1f[2 * f],     yf.v, ba, 0, 0, 0);
            const f32x4 a2 = __builtin_amdgcn_mfma_f32_16x16x32_f16(w1f[2 * f + 1], yf.v, bb, 0, 0, 0);
            union { half8 v; u32 iw[4]; } hf;
            #pragma unroll
            for (int w = 0; w < 4; ++w) {
                const f32x4& aa = (w < 2) ? a1 : a2;
                const u32 pk = pkrtz(aa[2 * (w & 1)], aa[2 * (w & 1) + 1]);
                u32 rl;
                asm("v_pk_max_f16 %0, %1, %2" : "=v"(rl) : "v"(pk), "v"(PZ));
                hf.iw[w] = rl;
            }
            if (f & 1) acc2b = __builtin_amdgcn_mfma_f32_16x16x32_f16(w2f[f], hf.v, acc2b, 0, 0, 0);
            else       acc2a = __builtin_amdgcn_mfma_f32_16x16x32_f16(w2f[f], hf.v, acc2a, 0, 0, 0);
        }

        // blend + store: lane stores channel 4*gqsw + r at its own column,
        // x comes from the staged f32 mids (no global re-read).
        const int col = start + 16 * t + p;
        #pragma unroll
        for (int r = 0; r < 4; ++r) {
            const float dx = acc2a[r] + acc2b[r];
            orow[(size_t)(4 * gqsw + r) * HW + col] = (mxB[r] + dx * um) * alive;
        }

        // (3) combine tile t+2 raws, rotate pipeline ------------------------
        half2v pcsD[4], pmD[4]; float mxD[4]; float cmD;
        combine(rr, pcsD, pmD, mxD, cmD);
        #pragma unroll
        for (int w = 0; w < 4; ++w) {
            pcsA[w] = pcsB[w];
            pcsB[w] = pcsC[w]; pmB[w] = pmC[w];
            pcsC[w] = pcsD[w]; pmC[w] = pmD[w];
        }
        #pragma unroll
        for (int j = 0; j < 4; ++j) { mxB[j] = mxC[j]; mxC[j] = mxD[j]; }
        cmA = cmB; cmB = cmC; cmC = cmD;
        nzB = nzC; nzC = nzD;
    }
}

extern "C" void kernel_launch(void* const* d_in, const int* in_sizes, int n_in,
                              void* d_out, int out_size, void* d_ws, size_t ws_size,
                              hipStream_t stream)
{
    const float* x     = (const float*)d_in[0];
    const float* noise = (const float*)d_in[1];
    const float* w1w   = (const float*)d_in[2];
    const float* w1b   = (const float*)d_in[3];
    const float* w2w   = (const float*)d_in[4];
    float* out = (float*)d_out;

    nca_mfma_kernel<<<1024, 256, 0, stream>>>(x, noise, w1w, w1b, w2w, out);
}